// Round 9
// baseline (90.299 us; speedup 1.0000x reference)
//
#include <hip/hip_runtime.h>
#include <math.h>

// Fuzzy LeNet-5, Yager p=1 == Lukasiewicz: T(a,b)=max(0,a+b-1).
// Fuzzy conv == max-plus conv: out = relu(max_{c,kh,kw}(x+w) - 1).
// maxpool2 folds into the conv via dilated 6x6 weights:
//   W'[uy][ux] = max_{dy,dx in {0,1}, uy-dy,ux-dx in [0,5)} w[uy-dy][ux-dx]
//
// R8 post-mortem: w3/wd register prefetch removed global latency (19.7us).
// R9: conv phases were LDS-issue-bound at b64 granularity -> all LDS reads
// vectorized to ds_read_b128 via alignment padding:
//   image rows padded to 36 floats (16B-aligned), conv1 reads 5xb128/(task,uy)
//   a1 rows padded to 16 floats, conv2 reads 4xb128/(task,uy)
//   dilated weights padded to 8-float rows, 2xb128 each
// Channel-partials combined via LDS atomicMax on relu'd float bits (exact:
// relu>=0 floats order as uints; relu(max-1)=max(relu(p-1))).

#define NT 1024
#define ROWS 36                 // padded image row stride (16B-aligned)
#define PLANE (32 * ROWS)       // 1152 floats

__global__ __launch_bounds__(NT) void fused_lenet(
    const float* __restrict__ x,   // [B,3,32,32]
    const float* __restrict__ w1,  // [6,3,5,5]
    const float* __restrict__ w2,  // [16,6,5,5]
    const float* __restrict__ w3,  // [120,16,5,5]
    const float* __restrict__ wd,  // [120,84]
    const float* __restrict__ wf,  // [84,10]
    const float* __restrict__ bfv, // [10]
    float* __restrict__ out)       // [B,10]
{
    const int img = blockIdx.x;
    const int tid = threadIdx.x;

    __shared__ __align__(16) float s_in[3 * PLANE];     // 13824 B
    __shared__ __align__(16) float s_w1d[864];          // [oc][c][uy][8]
    __shared__ __align__(16) float s_w2d[4608];         // [oc][c][uy][8]
    __shared__ __align__(16) unsigned s_a1u[1344];      // [c][14][16] relu bits
    __shared__ __align__(16) unsigned s_a2u[400];       // [16][5][5] relu bits
    __shared__ float s_a3[120];
    __shared__ float s_a4[84];

    // ---- Prefetch w3 fragments into registers (in flight through A..D)
    float4 w3p[13];
    if (tid < 960) {
        const int o = tid >> 3, q = tid & 7;
        const float4* wv = (const float4*)(w3 + o * 400);
        #pragma unroll
        for (int i = 0; i < 13; ++i) {
            int l = q + 8 * i; if (l > 99) l = 99;
            w3p[i] = wv[l];
        }
    }

    // ---- Phase A: stage image (float4, padded rows) + zero accums + dilate w1
    {
        if (tid < 768) {   // 3 planes x 32 rows x 8 float4
            const int c = tid >> 8, rem = tid & 255, r = rem >> 3, col4 = rem & 7;
            ((float4*)s_in)[c * (PLANE / 4) + r * 9 + col4] =
                ((const float4*)(x + img * 3072))[tid];
        }
        for (int i = tid; i < 1344; i += NT) s_a1u[i] = 0u;
        if (tid < 400) s_a2u[tid] = 0u;
        if (tid < 648) {
            const int oc = tid / 108, u = tid - oc * 108;
            const int c = u / 36, v = u - c * 36;
            const int r = v / 6, col = v - r * 6;
            const float* raw = w1 + (oc * 3 + c) * 25;
            float m = -1e30f;
            #pragma unroll
            for (int dy = 0; dy < 2; ++dy) {
                const int kh = r - dy;
                if ((unsigned)kh > 4u) continue;
                #pragma unroll
                for (int dx = 0; dx < 2; ++dx) {
                    const int kw = col - dx;
                    if ((unsigned)kw > 4u) continue;
                    m = fmaxf(m, raw[kh * 5 + kw]);
                }
            }
            s_w1d[((oc * 3 + c) * 6 + r) * 8 + col] = m;
        }
    }
    __syncthreads();

    // ---- Phase C: conv1 partials; 1008 tasks (c,oc,py,s,h), 3 uy x 7-px strip
    if (tid < 1008) {
        const int c = tid / 336;
        const int rr = tid - c * 336;
        const int oc = rr / 56;
        const int r2 = rr - oc * 56;
        const int py = r2 >> 2;
        const int s = (r2 >> 1) & 1;
        const int h = r2 & 1;
        float acc[7];
        #pragma unroll
        for (int j = 0; j < 7; ++j) acc[j] = -1e30f;
        const float* wbase = s_w1d + (oc * 3 + c) * 48 + h * 24;
        const float* xbase = s_in + c * PLANE + (2 * py + 3 * h) * ROWS + 12 * s;
        const int ofs = 2 * s;
        #pragma unroll
        for (int u = 0; u < 3; ++u) {
            float xv[20];
            #pragma unroll
            for (int i4 = 0; i4 < 5; ++i4)
                ((float4*)xv)[i4] = ((const float4*)(xbase + u * ROWS))[i4];
            float wv[8];
            ((float4*)wv)[0] = ((const float4*)(wbase + u * 8))[0];
            ((float4*)wv)[1] = ((const float4*)(wbase + u * 8))[1];
            #pragma unroll
            for (int j = 0; j < 7; ++j) {
                #pragma unroll
                for (int ux = 0; ux < 6; ++ux)
                    acc[j] = fmaxf(acc[j], xv[ofs + 2 * j + ux] + wv[ux]);
            }
        }
        const int obase = (oc * 14 + py) * 16 + 7 * s;
        #pragma unroll
        for (int j = 0; j < 7; ++j) {
            const float rl = fmaxf(acc[j] - 1.0f, 0.0f);
            atomicMax(&s_a1u[obase + j], __float_as_uint(rl));
        }
    }
    // dilate w2 from global (overlaps conv1 across waves; same barrier covers)
    for (int e = tid; e < 3456; e += NT) {
        const int oc = e / 216, u = e - oc * 216;
        const int c = u / 36, v = u - c * 36;
        const int r = v / 6, col = v - r * 6;
        const float* raw = w2 + (oc * 6 + c) * 25;
        float m = -1e30f;
        #pragma unroll
        for (int dy = 0; dy < 2; ++dy) {
            const int kh = r - dy;
            if ((unsigned)kh > 4u) continue;
            #pragma unroll
            for (int dx = 0; dx < 2; ++dx) {
                const int kw = col - dx;
                if ((unsigned)kw > 4u) continue;
                m = fmaxf(m, raw[kh * 5 + kw]);
            }
        }
        s_w2d[((oc * 6 + c) * 6 + r) * 8 + col] = m;
    }
    __syncthreads();

    // ---- Phase D: conv2 partials; 960 tasks (oc,py,c,h), 3 uy x 5-px row
    if (tid < 960) {
        const int oc = tid / 60;
        const int rr = tid - oc * 60;
        const int py = rr / 12;
        const int r2 = rr - py * 12;
        const int c = r2 >> 1;
        const int h = r2 & 1;
        float acc[5];
        #pragma unroll
        for (int j = 0; j < 5; ++j) acc[j] = -1e30f;
        const float* a1f = (const float*)s_a1u;
        const float* wbase = s_w2d + (oc * 6 + c) * 48 + h * 24;
        const float* xbase = a1f + (c * 14 + 2 * py + 3 * h) * 16;
        #pragma unroll
        for (int u = 0; u < 3; ++u) {
            float xv[16];
            #pragma unroll
            for (int i4 = 0; i4 < 4; ++i4)
                ((float4*)xv)[i4] = ((const float4*)(xbase + u * 16))[i4];
            float wv[8];
            ((float4*)wv)[0] = ((const float4*)(wbase + u * 8))[0];
            ((float4*)wv)[1] = ((const float4*)(wbase + u * 8))[1];
            #pragma unroll
            for (int j = 0; j < 5; ++j) {
                #pragma unroll
                for (int ux = 0; ux < 6; ++ux)
                    acc[j] = fmaxf(acc[j], xv[2 * j + ux] + wv[ux]);
            }
        }
        const int obase = oc * 25 + py * 5;
        #pragma unroll
        for (int j = 0; j < 5; ++j) {
            const float rl = fmaxf(acc[j] - 1.0f, 0.0f);
            atomicMax(&s_a2u[obase + j], __float_as_uint(rl));
        }
    }
    // prefetch wd for the dense phase (in flight during E)
    float wdp[15];
    if (tid < 672) {
        const int o = tid >> 3, q = tid & 7;
        #pragma unroll
        for (int i = 0; i < 15; ++i)
            wdp[i] = wd[(q * 15 + i) * 84 + o];
    }
    __syncthreads();

    // ---- Phase E: L3 [16,5,5]->[120]; 8 threads/output, prefetched w3
    if (tid < 960) {
        const int o = tid >> 3, q = tid & 7;
        const float4* av = (const float4*)(const float*)s_a2u;
        float m = -1e30f;
        #pragma unroll
        for (int i = 0; i < 13; ++i) {
            int l = q + 8 * i; if (l > 99) l = 99;
            const float4 a = av[l];
            const float4 w = w3p[i];
            m = fmaxf(m, fmaxf(fmaxf(a.x + w.x, a.y + w.y),
                               fmaxf(a.z + w.z, a.w + w.w)));
        }
        m = fmaxf(m, __shfl_xor(m, 1));
        m = fmaxf(m, __shfl_xor(m, 2));
        m = fmaxf(m, __shfl_xor(m, 4));
        if (q == 0) s_a3[o] = fmaxf(m - 1.0f, 0.0f);
    }
    __syncthreads();

    // ---- Phase F: dense [120]->[84] + tanh; 8 threads/output, prefetched wd
    if (tid < 672) {
        const int o = tid >> 3, q = tid & 7;
        float acc = 0.0f;
        #pragma unroll
        for (int i = 0; i < 15; ++i)
            acc = fmaf(s_a3[q * 15 + i], wdp[i], acc);
        acc += __shfl_xor(acc, 1);
        acc += __shfl_xor(acc, 2);
        acc += __shfl_xor(acc, 4);
        if (q == 0) s_a4[o] = tanhf(acc);
    }
    __syncthreads();

    // ---- Phase G: fc [84]->[10] + bias + log_softmax, single wave
    if (tid < 64) {
        float acc = 0.0f;
        if (tid < 40) {
            const int o = tid >> 2, q = tid & 3;
            #pragma unroll 7
            for (int i = 0; i < 21; ++i) {
                const int k = q * 21 + i;
                acc = fmaf(s_a4[k], wf[k * 10 + o], acc);
            }
            acc += __shfl_xor(acc, 1);
            acc += __shfl_xor(acc, 2);
            acc += bfv[o];
        }
        const float lg = __shfl(acc, (tid < 10) ? tid * 4 : 0);
        if (tid < 16) {
            float v = (tid < 10) ? lg : -1e30f;
            #pragma unroll
            for (int d = 1; d < 16; d <<= 1)
                v = fmaxf(v, __shfl_xor(v, d));
            float e = (tid < 10) ? expf(lg - v) : 0.0f;
            float ssum = e;
            #pragma unroll
            for (int d = 1; d < 16; d <<= 1)
                ssum += __shfl_xor(ssum, d);
            if (tid < 10)
                out[img * 10 + tid] = lg - v - logf(ssum);
        }
    }
}

extern "C" void kernel_launch(void* const* d_in, const int* in_sizes, int n_in,
                              void* d_out, int out_size, void* d_ws, size_t ws_size,
                              hipStream_t stream) {
    const float* x   = (const float*)d_in[0];
    const float* w1  = (const float*)d_in[1];
    const float* w2  = (const float*)d_in[2];
    const float* w3  = (const float*)d_in[3];
    const float* wd  = (const float*)d_in[4];
    const float* wf  = (const float*)d_in[5];
    const float* bfv = (const float*)d_in[6];
    float* out = (float*)d_out;

    const int B = in_sizes[0] / (3 * 32 * 32);
    fused_lenet<<<dim3(B), dim3(NT), 0, stream>>>(
        x, w1, w2, w3, wd, wf, bfv, out);
}

// Round 10
// 77.164 us; speedup vs baseline: 1.1702x; 1.1702x over previous
//
#include <hip/hip_runtime.h>
#include <math.h>

// Fuzzy LeNet-5, Yager p=1 == Lukasiewicz: T(a,b)=max(0,a+b-1).
// Fuzzy conv == max-plus conv: out = relu(max_{c,kh,kw}(x+w) - 1).
// maxpool2 folds into the conv via dilated 6x6 weights:
//   W'[uy][ux] = max_{dy,dx in {0,1}, uy-dy,ux-dx in [0,5)} w[uy-dy][ux-dx]
//
// R9 post-mortem: b128/power-of-2-stride LDS layout REGRESSED (bank conflicts
// + VGPR pressure). Reverted to R8's b64 odd-stride layout (proven 19.7us).
// R10 deltas vs R8 (both remove exposed global latency, nothing else):
//  - w2 raw staged to LDS in phase A (rides the image-stage load window);
//    phase C dilation reads LDS only.
//  - wf+bf staged to LDS in phase A; phase G is LDS-only at the tail.
// Channel-partials combined via LDS atomicMax on relu'd float bits (exact:
// relu>=0 floats order as uints; relu(max-1)=max(relu(p-1))).

#define NT 1024
#define ROWS 34                 // padded image row stride
#define PLANE (32 * ROWS)       // 1088

__global__ __launch_bounds__(NT) void fused_lenet(
    const float* __restrict__ x,   // [B,3,32,32]
    const float* __restrict__ w1,  // [6,3,5,5]
    const float* __restrict__ w2,  // [16,6,5,5]
    const float* __restrict__ w3,  // [120,16,5,5]
    const float* __restrict__ wd,  // [120,84]
    const float* __restrict__ wf,  // [84,10]
    const float* __restrict__ bfv, // [10]
    float* __restrict__ out)       // [B,10]
{
    const int img = blockIdx.x;
    const int tid = threadIdx.x;

    __shared__ float s_in[3 * PLANE];          // 13056 B
    __shared__ float s_w1d[648];               // [oc][c][uy][6]
    __shared__ float s_w2d[3456];              // [oc][c][uy][6]
    __shared__ float s_w2r[2400];              // raw w2
    __shared__ float s_wf[850];                // wf[840] + bf[10]
    __shared__ unsigned s_a1u[1176];           // conv1 out, relu'd float bits
    __shared__ unsigned s_a2u[400];            // conv2 out, relu'd float bits
    __shared__ float s_a3[120];
    __shared__ float s_a4[84];

    // ---- Prefetch w3 fragments into registers (in flight through A..D)
    float4 w3p[13];
    if (tid < 960) {
        const int o = tid >> 3, q = tid & 7;
        const float4* wv = (const float4*)(w3 + o * 400);
        #pragma unroll
        for (int i = 0; i < 13; ++i) {
            int l = q + 8 * i; if (l > 99) l = 99;
            w3p[i] = wv[l];
        }
    }

    // ---- Phase A: stage image + w2 raw + wf/bf + zero accums + dilate w1
    {
        const float2* src = (const float2*)(x + img * 3072);
        for (int i = tid; i < 1536; i += NT) {
            const int c = i >> 9, rem = i & 511, r = rem >> 4, col2 = rem & 15;
            ((float2*)s_in)[c * (PLANE / 2) + r * (ROWS / 2) + col2] = src[i];
        }
        for (int i = tid; i < 1200; i += NT)
            ((float2*)s_w2r)[i] = ((const float2*)w2)[i];
        if (tid < 850)
            s_wf[tid] = (tid < 840) ? wf[tid] : bfv[tid - 840];
        for (int i = tid; i < 1176; i += NT) s_a1u[i] = 0u;
        if (tid < 400) s_a2u[tid] = 0u;
        if (tid < 648) {
            const int oc = tid / 108, u = tid - oc * 108;
            const int c = u / 36, v = u - c * 36;
            const int r = v / 6, col = v - r * 6;
            const float* raw = w1 + (oc * 3 + c) * 25;
            float m = -1e30f;
            #pragma unroll
            for (int dy = 0; dy < 2; ++dy) {
                const int kh = r - dy;
                if ((unsigned)kh > 4u) continue;
                #pragma unroll
                for (int dx = 0; dx < 2; ++dx) {
                    const int kw = col - dx;
                    if ((unsigned)kw > 4u) continue;
                    m = fmaxf(m, raw[kh * 5 + kw]);
                }
            }
            s_w1d[tid] = m;
        }
    }
    __syncthreads();

    // ---- Phase C: conv1 partials; 1008 tasks (c,oc,py,s,h), 3 uy x 7-px strip
    if (tid < 1008) {
        const int c = tid / 336;
        const int rr = tid - c * 336;
        const int oc = rr / 56;
        const int r2 = rr - oc * 56;
        const int py = r2 >> 2;
        const int s = (r2 >> 1) & 1;
        const int h = r2 & 1;
        float acc[7];
        #pragma unroll
        for (int j = 0; j < 7; ++j) acc[j] = -1e30f;
        const float* wbase = s_w1d + (oc * 3 + c) * 36 + h * 18;
        const float* xbase = s_in + c * PLANE + (2 * py + 3 * h) * ROWS + 14 * s;
        #pragma unroll
        for (int u = 0; u < 3; ++u) {
            const float* xr = xbase + u * ROWS;
            float xv[18];
            #pragma unroll
            for (int i2 = 0; i2 < 9; ++i2)
                ((float2*)xv)[i2] = ((const float2*)xr)[i2];
            float wv[6];
            #pragma unroll
            for (int i2 = 0; i2 < 3; ++i2)
                ((float2*)wv)[i2] = ((const float2*)(wbase + u * 6))[i2];
            #pragma unroll
            for (int j = 0; j < 7; ++j) {
                #pragma unroll
                for (int ux = 0; ux < 6; ++ux)
                    acc[j] = fmaxf(acc[j], xv[2 * j + ux] + wv[ux]);
            }
        }
        const int obase = oc * 196 + py * 14 + 7 * s;
        #pragma unroll
        for (int j = 0; j < 7; ++j) {
            const float rl = fmaxf(acc[j] - 1.0f, 0.0f);
            atomicMax(&s_a1u[obase + j], __float_as_uint(rl));
        }
    }
    // dilate w2 from LDS raw copy (no global latency; same barrier covers)
    for (int e = tid; e < 3456; e += NT) {
        const int oc = e / 216, u = e - oc * 216;
        const int c = u / 36, v = u - c * 36;
        const int r = v / 6, col = v - r * 6;
        const float* raw = s_w2r + (oc * 6 + c) * 25;
        float m = -1e30f;
        #pragma unroll
        for (int dy = 0; dy < 2; ++dy) {
            const int kh = r - dy;
            if ((unsigned)kh > 4u) continue;
            #pragma unroll
            for (int dx = 0; dx < 2; ++dx) {
                const int kw = col - dx;
                if ((unsigned)kw > 4u) continue;
                m = fmaxf(m, raw[kh * 5 + kw]);
            }
        }
        s_w2d[e] = m;
    }
    __syncthreads();

    // ---- Phase D: conv2 partials; 960 tasks (oc,py,c,h), 3 uy x 5-px row
    if (tid < 960) {
        const int oc = tid / 60;
        const int rr = tid - oc * 60;
        const int py = rr / 12;
        const int r2 = rr - py * 12;
        const int c = r2 >> 1;
        const int h = r2 & 1;
        float acc[5];
        #pragma unroll
        for (int j = 0; j < 5; ++j) acc[j] = -1e30f;
        const float* a1f = (const float*)s_a1u;
        const float* wbase = s_w2d + (oc * 6 + c) * 36 + h * 18;
        const float* xbase = a1f + c * 196 + (2 * py + 3 * h) * 14;
        #pragma unroll
        for (int u = 0; u < 3; ++u) {
            const float* xr = xbase + u * 14;
            float xv[14];
            #pragma unroll
            for (int i2 = 0; i2 < 7; ++i2)
                ((float2*)xv)[i2] = ((const float2*)xr)[i2];
            float wv[6];
            #pragma unroll
            for (int i2 = 0; i2 < 3; ++i2)
                ((float2*)wv)[i2] = ((const float2*)(wbase + u * 6))[i2];
            #pragma unroll
            for (int j = 0; j < 5; ++j) {
                #pragma unroll
                for (int ux = 0; ux < 6; ++ux)
                    acc[j] = fmaxf(acc[j], xv[2 * j + ux] + wv[ux]);
            }
        }
        const int obase = oc * 25 + py * 5;
        #pragma unroll
        for (int j = 0; j < 5; ++j) {
            const float rl = fmaxf(acc[j] - 1.0f, 0.0f);
            atomicMax(&s_a2u[obase + j], __float_as_uint(rl));
        }
    }
    // prefetch wd for the dense phase (in flight during E)
    float wdp[15];
    if (tid < 672) {
        const int o = tid >> 3, q = tid & 7;
        #pragma unroll
        for (int i = 0; i < 15; ++i)
            wdp[i] = wd[(q * 15 + i) * 84 + o];
    }
    __syncthreads();

    // ---- Phase E: L3 [16,5,5]->[120]; 8 threads/output, prefetched w3
    if (tid < 960) {
        const int o = tid >> 3, q = tid & 7;
        const float4* av = (const float4*)(const float*)s_a2u;
        float m = -1e30f;
        #pragma unroll
        for (int i = 0; i < 13; ++i) {
            int l = q + 8 * i; if (l > 99) l = 99;
            const float4 a = av[l];
            const float4 w = w3p[i];
            m = fmaxf(m, fmaxf(fmaxf(a.x + w.x, a.y + w.y),
                               fmaxf(a.z + w.z, a.w + w.w)));
        }
        m = fmaxf(m, __shfl_xor(m, 1));
        m = fmaxf(m, __shfl_xor(m, 2));
        m = fmaxf(m, __shfl_xor(m, 4));
        if (q == 0) s_a3[o] = fmaxf(m - 1.0f, 0.0f);
    }
    __syncthreads();

    // ---- Phase F: dense [120]->[84] + tanh; 8 threads/output, prefetched wd
    if (tid < 672) {
        const int o = tid >> 3, q = tid & 7;
        float acc = 0.0f;
        #pragma unroll
        for (int i = 0; i < 15; ++i)
            acc = fmaf(s_a3[q * 15 + i], wdp[i], acc);
        acc += __shfl_xor(acc, 1);
        acc += __shfl_xor(acc, 2);
        acc += __shfl_xor(acc, 4);
        if (q == 0) s_a4[o] = tanhf(acc);
    }
    __syncthreads();

    // ---- Phase G: fc [84]->[10] + bias + log_softmax, single wave, LDS-only
    if (tid < 64) {
        float acc = 0.0f;
        if (tid < 40) {
            const int o = tid >> 2, q = tid & 3;
            #pragma unroll 7
            for (int i = 0; i < 21; ++i) {
                const int k = q * 21 + i;
                acc = fmaf(s_a4[k], s_wf[k * 10 + o], acc);
            }
            acc += __shfl_xor(acc, 1);
            acc += __shfl_xor(acc, 2);
            acc += s_wf[840 + o];
        }
        const float lg = __shfl(acc, (tid < 10) ? tid * 4 : 0);
        if (tid < 16) {
            float v = (tid < 10) ? lg : -1e30f;
            #pragma unroll
            for (int d = 1; d < 16; d <<= 1)
                v = fmaxf(v, __shfl_xor(v, d));
            float e = (tid < 10) ? expf(lg - v) : 0.0f;
            float ssum = e;
            #pragma unroll
            for (int d = 1; d < 16; d <<= 1)
                ssum += __shfl_xor(ssum, d);
            if (tid < 10)
                out[img * 10 + tid] = lg - v - logf(ssum);
        }
    }
}

extern "C" void kernel_launch(void* const* d_in, const int* in_sizes, int n_in,
                              void* d_out, int out_size, void* d_ws, size_t ws_size,
                              hipStream_t stream) {
    const float* x   = (const float*)d_in[0];
    const float* w1  = (const float*)d_in[1];
    const float* w2  = (const float*)d_in[2];
    const float* w3  = (const float*)d_in[3];
    const float* wd  = (const float*)d_in[4];
    const float* wf  = (const float*)d_in[5];
    const float* bfv = (const float*)d_in[6];
    float* out = (float*)d_out;

    const int B = in_sizes[0] / (3 * 32 * 32);
    fused_lenet<<<dim3(B), dim3(NT), 0, stream>>>(
        x, w1, w2, w3, wd, wf, bfv, out);
}

// Round 11
// 75.804 us; speedup vs baseline: 1.1912x; 1.0179x over previous
//
#include <hip/hip_runtime.h>
#include <math.h>

// Fuzzy LeNet-5, Yager p=1 == Lukasiewicz: T(a,b)=max(0,a+b-1).
// Fuzzy conv == max-plus conv: out = relu(max_{c,kh,kw}(x+w) - 1).
// maxpool2 folds into the conv via dilated 6x6 weights:
//   W'[uy][ux] = max_{dy,dx in {0,1}, uy-dy,ux-dx in [0,5)} w[uy-dy][ux-dx]
//
// R10 post-mortem: kernel ~18.9us; LDS issue (conv x re-reads per oc) is the
// largest consumer. R11: oc-grouped conv tasks reuse each x row-span across
// 3 (conv1) / 4 (conv2) output channels -> conv1 LDS reads 567->284 wave-
// insts, conv2 450->214. w3 register prefetch moved from kernel entry to
// after the conv1 body (frees 52 VGPRs during acc-heavy conv1; still covered
// by conv2 + barriers before phase E consumes it).
// Channel/h-partials combined via LDS atomicMax on relu'd float bits (exact:
// relu>=0 floats order as uints; relu(max-1)=max(relu(p-1))).

#define NT 1024
#define ROWS 34                 // padded image row stride
#define PLANE (32 * ROWS)       // 1088

__global__ __launch_bounds__(NT) void fused_lenet(
    const float* __restrict__ x,   // [B,3,32,32]
    const float* __restrict__ w1,  // [6,3,5,5]
    const float* __restrict__ w2,  // [16,6,5,5]
    const float* __restrict__ w3,  // [120,16,5,5]
    const float* __restrict__ wd,  // [120,84]
    const float* __restrict__ wf,  // [84,10]
    const float* __restrict__ bfv, // [10]
    float* __restrict__ out)       // [B,10]
{
    const int img = blockIdx.x;
    const int tid = threadIdx.x;

    __shared__ float s_in[3 * PLANE];          // 13056 B
    __shared__ float s_w1d[648];               // [oc][c][uy][6]
    __shared__ float s_w2d[3456];              // [oc][c][uy][6]
    __shared__ float s_w2r[2400];              // raw w2
    __shared__ float s_wf[850];                // wf[840] + bf[10]
    __shared__ unsigned s_a1u[1176];           // conv1 out, relu'd float bits
    __shared__ unsigned s_a2u[400];            // conv2 out, relu'd float bits
    __shared__ float s_a3[120];
    __shared__ float s_a4[84];

    float4 w3p[13];   // filled after conv1 body, consumed in phase E

    // ---- Phase A: stage image + w2 raw + wf/bf + zero accums + dilate w1
    {
        const float2* src = (const float2*)(x + img * 3072);
        for (int i = tid; i < 1536; i += NT) {
            const int c = i >> 9, rem = i & 511, r = rem >> 4, col2 = rem & 15;
            ((float2*)s_in)[c * (PLANE / 2) + r * (ROWS / 2) + col2] = src[i];
        }
        for (int i = tid; i < 1200; i += NT)
            ((float2*)s_w2r)[i] = ((const float2*)w2)[i];
        if (tid < 850)
            s_wf[tid] = (tid < 840) ? wf[tid] : bfv[tid - 840];
        for (int i = tid; i < 1176; i += NT) s_a1u[i] = 0u;
        if (tid < 400) s_a2u[tid] = 0u;
        if (tid < 648) {
            const int oc = tid / 108, u = tid - oc * 108;
            const int c = u / 36, v = u - c * 36;
            const int r = v / 6, col = v - r * 6;
            const float* raw = w1 + (oc * 3 + c) * 25;
            float m = -1e30f;
            #pragma unroll
            for (int dy = 0; dy < 2; ++dy) {
                const int kh = r - dy;
                if ((unsigned)kh > 4u) continue;
                #pragma unroll
                for (int dx = 0; dx < 2; ++dx) {
                    const int kw = col - dx;
                    if ((unsigned)kw > 4u) continue;
                    m = fmaxf(m, raw[kh * 5 + kw]);
                }
            }
            s_w1d[tid] = m;
        }
    }
    __syncthreads();

    // ---- Phase C: conv1 partials; 336 tasks (c,ocg,py,s,h), 3 oc per task,
    //      3 uy x 7-px strip, x row loaded once per uy and reused across oc
    if (tid < 336) {
        const int c = tid / 112;
        const int r = tid - c * 112;
        const int ocg = r / 56;
        const int r2 = r - ocg * 56;
        const int py = r2 >> 2;
        const int s = (r2 >> 1) & 1;
        const int h = r2 & 1;
        float acc[3][7];
        #pragma unroll
        for (int o = 0; o < 3; ++o)
            #pragma unroll
            for (int j = 0; j < 7; ++j) acc[o][j] = -1e30f;
        const float* xbase = s_in + c * PLANE + (2 * py + 3 * h) * ROWS + 14 * s;
        #pragma unroll
        for (int u = 0; u < 3; ++u) {
            float xv[18];
            #pragma unroll
            for (int i2 = 0; i2 < 9; ++i2)
                ((float2*)xv)[i2] = ((const float2*)(xbase + u * ROWS))[i2];
            #pragma unroll
            for (int o = 0; o < 3; ++o) {
                const float* wbase =
                    s_w1d + ((ocg * 3 + o) * 3 + c) * 36 + h * 18 + u * 6;
                float wv[6];
                #pragma unroll
                for (int i2 = 0; i2 < 3; ++i2)
                    ((float2*)wv)[i2] = ((const float2*)wbase)[i2];
                #pragma unroll
                for (int j = 0; j < 7; ++j) {
                    #pragma unroll
                    for (int ux = 0; ux < 6; ++ux)
                        acc[o][j] = fmaxf(acc[o][j], xv[2 * j + ux] + wv[ux]);
                }
            }
        }
        #pragma unroll
        for (int o = 0; o < 3; ++o) {
            const int obase = (ocg * 3 + o) * 196 + py * 14 + 7 * s;
            #pragma unroll
            for (int j = 0; j < 7; ++j) {
                const float rl = fmaxf(acc[o][j] - 1.0f, 0.0f);
                atomicMax(&s_a1u[obase + j], __float_as_uint(rl));
            }
        }
    }
    // prefetch w3 into registers (in flight through conv2 + barriers, used E)
    if (tid < 960) {
        const int o = tid >> 3, q = tid & 7;
        const float4* wv = (const float4*)(w3 + o * 400);
        #pragma unroll
        for (int i = 0; i < 13; ++i) {
            int l = q + 8 * i; if (l > 99) l = 99;
            w3p[i] = wv[l];
        }
    }
    // dilate w2 from LDS raw copy (no global latency; same barrier covers)
    for (int e = tid; e < 3456; e += NT) {
        const int oc = e / 216, u = e - oc * 216;
        const int c = u / 36, v = u - c * 36;
        const int r = v / 6, col = v - r * 6;
        const float* raw = s_w2r + (oc * 6 + c) * 25;
        float m = -1e30f;
        #pragma unroll
        for (int dy = 0; dy < 2; ++dy) {
            const int kh = r - dy;
            if ((unsigned)kh > 4u) continue;
            #pragma unroll
            for (int dx = 0; dx < 2; ++dx) {
                const int kw = col - dx;
                if ((unsigned)kw > 4u) continue;
                m = fmaxf(m, raw[kh * 5 + kw]);
            }
        }
        s_w2d[e] = m;
    }
    __syncthreads();

    // ---- Phase D: conv2 partials; 240 tasks (ocq,py,c,h), 4 oc per task,
    //      3 uy x 5-px row, x row loaded once per uy and reused across oc
    if (tid < 240) {
        const int ocq = tid / 60;
        const int r = tid - ocq * 60;
        const int py = r / 12;
        const int r2 = r - py * 12;
        const int c = r2 >> 1;
        const int h = r2 & 1;
        float acc[4][5];
        #pragma unroll
        for (int o = 0; o < 4; ++o)
            #pragma unroll
            for (int j = 0; j < 5; ++j) acc[o][j] = -1e30f;
        const float* a1f = (const float*)s_a1u;
        const float* xbase = a1f + c * 196 + (2 * py + 3 * h) * 14;
        #pragma unroll
        for (int u = 0; u < 3; ++u) {
            float xv[14];
            #pragma unroll
            for (int i2 = 0; i2 < 7; ++i2)
                ((float2*)xv)[i2] = ((const float2*)(xbase + u * 14))[i2];
            #pragma unroll
            for (int o = 0; o < 4; ++o) {
                const float* wbase =
                    s_w2d + ((ocq * 4 + o) * 6 + c) * 36 + h * 18 + u * 6;
                float wv[6];
                #pragma unroll
                for (int i2 = 0; i2 < 3; ++i2)
                    ((float2*)wv)[i2] = ((const float2*)wbase)[i2];
                #pragma unroll
                for (int j = 0; j < 5; ++j) {
                    #pragma unroll
                    for (int ux = 0; ux < 6; ++ux)
                        acc[o][j] = fmaxf(acc[o][j], xv[2 * j + ux] + wv[ux]);
                }
            }
        }
        #pragma unroll
        for (int o = 0; o < 4; ++o) {
            const int obase = (ocq * 4 + o) * 25 + py * 5;
            #pragma unroll
            for (int j = 0; j < 5; ++j) {
                const float rl = fmaxf(acc[o][j] - 1.0f, 0.0f);
                atomicMax(&s_a2u[obase + j], __float_as_uint(rl));
            }
        }
    }
    // prefetch wd for the dense phase (in flight during E)
    float wdp[15];
    if (tid < 672) {
        const int o = tid >> 3, q = tid & 7;
        #pragma unroll
        for (int i = 0; i < 15; ++i)
            wdp[i] = wd[(q * 15 + i) * 84 + o];
    }
    __syncthreads();

    // ---- Phase E: L3 [16,5,5]->[120]; 8 threads/output, prefetched w3
    if (tid < 960) {
        const int o = tid >> 3, q = tid & 7;
        const float4* av = (const float4*)(const float*)s_a2u;
        float m = -1e30f;
        #pragma unroll
        for (int i = 0; i < 13; ++i) {
            int l = q + 8 * i; if (l > 99) l = 99;
            const float4 a = av[l];
            const float4 w = w3p[i];
            m = fmaxf(m, fmaxf(fmaxf(a.x + w.x, a.y + w.y),
                               fmaxf(a.z + w.z, a.w + w.w)));
        }
        m = fmaxf(m, __shfl_xor(m, 1));
        m = fmaxf(m, __shfl_xor(m, 2));
        m = fmaxf(m, __shfl_xor(m, 4));
        if (q == 0) s_a3[o] = fmaxf(m - 1.0f, 0.0f);
    }
    __syncthreads();

    // ---- Phase F: dense [120]->[84] + tanh; 8 threads/output, prefetched wd
    if (tid < 672) {
        const int o = tid >> 3, q = tid & 7;
        float acc = 0.0f;
        #pragma unroll
        for (int i = 0; i < 15; ++i)
            acc = fmaf(s_a3[q * 15 + i], wdp[i], acc);
        acc += __shfl_xor(acc, 1);
        acc += __shfl_xor(acc, 2);
        acc += __shfl_xor(acc, 4);
        if (q == 0) s_a4[o] = tanhf(acc);
    }
    __syncthreads();

    // ---- Phase G: fc [84]->[10] + bias + log_softmax, single wave, LDS-only
    if (tid < 64) {
        float acc = 0.0f;
        if (tid < 40) {
            const int o = tid >> 2, q = tid & 3;
            #pragma unroll 7
            for (int i = 0; i < 21; ++i) {
                const int k = q * 21 + i;
                acc = fmaf(s_a4[k], s_wf[k * 10 + o], acc);
            }
            acc += __shfl_xor(acc, 1);
            acc += __shfl_xor(acc, 2);
            acc += s_wf[840 + o];
        }
        const float lg = __shfl(acc, (tid < 10) ? tid * 4 : 0);
        if (tid < 16) {
            float v = (tid < 10) ? lg : -1e30f;
            #pragma unroll
            for (int d = 1; d < 16; d <<= 1)
                v = fmaxf(v, __shfl_xor(v, d));
            float e = (tid < 10) ? expf(lg - v) : 0.0f;
            float ssum = e;
            #pragma unroll
            for (int d = 1; d < 16; d <<= 1)
                ssum += __shfl_xor(ssum, d);
            if (tid < 10)
                out[img * 10 + tid] = lg - v - logf(ssum);
        }
    }
}

extern "C" void kernel_launch(void* const* d_in, const int* in_sizes, int n_in,
                              void* d_out, int out_size, void* d_ws, size_t ws_size,
                              hipStream_t stream) {
    const float* x   = (const float*)d_in[0];
    const float* w1  = (const float*)d_in[1];
    const float* w2  = (const float*)d_in[2];
    const float* w3  = (const float*)d_in[3];
    const float* wd  = (const float*)d_in[4];
    const float* wf  = (const float*)d_in[5];
    const float* bfv = (const float*)d_in[6];
    float* out = (float*)d_out;

    const int B = in_sizes[0] / (3 * 32 * 32);
    fused_lenet<<<dim3(B), dim3(NT), 0, stream>>>(
        x, w1, w2, w3, wd, wf, bfv, out);
}

// Round 12
// 74.184 us; speedup vs baseline: 1.2172x; 1.0218x over previous
//
#include <hip/hip_runtime.h>
#include <math.h>

// Fuzzy LeNet-5, Yager p=1 == Lukasiewicz: T(a,b)=max(0,a+b-1).
// Fuzzy conv == max-plus conv: out = relu(max_{c,kh,kw}(x+w) - 1).
// maxpool2 folds into the conv via dilated 6x6 weights:
//   W'[uy][ux] = max_{dy,dx in {0,1}, uy-dy,ux-dx in [0,5)} w[uy-dy][ux-dx]
//
// R11 post-mortem: C-window is LDS-issue-bound; w2 dilation was ~270 wave-
// insts of it. R12: row-formulation dilation (task = (oc,c,row): read 2 raw
// rows, running col-max, 3xb64 write) cuts w1 dilation to ~26 global-inst
// and w2 dilation to ~117 LDS-inst, pinned to waves 7-15 (tid>=448) so conv1
// waves 0-5 never touch it. wf staged as float2; tanh/exp/log via hw
// v_exp/v_log forms (error ~1e-7 vs 6.8e-2 threshold).
// Channel/h-partials combined via LDS atomicMax on relu'd float bits (exact:
// relu>=0 floats order as uints; relu(max-1)=max(relu(p-1))).

#define NT 1024
#define ROWS 34                 // padded image row stride
#define PLANE (32 * ROWS)       // 1088

__device__ __forceinline__ void dilate_row(const float* __restrict__ raw,
                                           int r, float* __restrict__ dst) {
    // dst[0..5] = max over kh in {r-1,r} cap [0,4], kw in {col-1,col} cap [0,4]
    const int rA = (r > 0) ? r - 1 : 0;
    const int rB = (r < 5) ? r : 4;
    float t0 = fmaxf(raw[rA * 5 + 0], raw[rB * 5 + 0]);
    float t1 = fmaxf(raw[rA * 5 + 1], raw[rB * 5 + 1]);
    float t2 = fmaxf(raw[rA * 5 + 2], raw[rB * 5 + 2]);
    float t3 = fmaxf(raw[rA * 5 + 3], raw[rB * 5 + 3]);
    float t4 = fmaxf(raw[rA * 5 + 4], raw[rB * 5 + 4]);
    float2* d = (float2*)dst;
    d[0] = make_float2(t0, fmaxf(t0, t1));
    d[1] = make_float2(fmaxf(t1, t2), fmaxf(t2, t3));
    d[2] = make_float2(fmaxf(t3, t4), t4);
}

__global__ __launch_bounds__(NT) void fused_lenet(
    const float* __restrict__ x,   // [B,3,32,32]
    const float* __restrict__ w1,  // [6,3,5,5]
    const float* __restrict__ w2,  // [16,6,5,5]
    const float* __restrict__ w3,  // [120,16,5,5]
    const float* __restrict__ wd,  // [120,84]
    const float* __restrict__ wf,  // [84,10]
    const float* __restrict__ bfv, // [10]
    float* __restrict__ out)       // [B,10]
{
    const int img = blockIdx.x;
    const int tid = threadIdx.x;

    __shared__ float s_in[3 * PLANE];          // 13056 B
    __shared__ float s_w1d[648];               // [oc][c][uy][6]
    __shared__ float s_w2d[3456];              // [oc][c][uy][6]
    __shared__ float s_w2r[2400];              // raw w2
    __shared__ float s_wf[850];                // wf[840] + bf[10]
    __shared__ unsigned s_a1u[1176];           // conv1 out, relu'd float bits
    __shared__ unsigned s_a2u[400];            // conv2 out, relu'd float bits
    __shared__ float s_a3[120];
    __shared__ float s_a4[84];

    float4 w3p[13];   // filled after conv1 body, consumed in phase E

    // ---- Phase A: stage image + w2 raw + wf/bf + zero accums + dilate w1
    {
        const float2* src = (const float2*)(x + img * 3072);
        for (int i = tid; i < 1536; i += NT) {
            const int c = i >> 9, rem = i & 511, r = rem >> 4, col2 = rem & 15;
            ((float2*)s_in)[c * (PLANE / 2) + r * (ROWS / 2) + col2] = src[i];
        }
        for (int i = tid; i < 1200; i += NT)
            ((float2*)s_w2r)[i] = ((const float2*)w2)[i];
        if (tid < 420) ((float2*)s_wf)[tid] = ((const float2*)wf)[tid];
        if (tid >= 448 && tid < 458) s_wf[840 + tid - 448] = bfv[tid - 448];
        for (int i = tid; i < 1176; i += NT) s_a1u[i] = 0u;
        if (tid < 400) s_a2u[tid] = 0u;
        if (tid >= 512 && tid < 620) {          // w1 dilation: 108 row-tasks
            const int e = tid - 512;
            const int occ = e / 6, r = e - occ * 6;   // occ = oc*3+c
            dilate_row(w1 + occ * 25, r, s_w1d + occ * 36 + r * 6);
        }
    }
    __syncthreads();

    // ---- Phase C: conv1 partials; 336 tasks (c,ocg,py,s,h), 3 oc per task,
    //      3 uy x 7-px strip, x row loaded once per uy and reused across oc
    if (tid < 336) {
        const int c = tid / 112;
        const int r = tid - c * 112;
        const int ocg = r / 56;
        const int r2 = r - ocg * 56;
        const int py = r2 >> 2;
        const int s = (r2 >> 1) & 1;
        const int h = r2 & 1;
        float acc[3][7];
        #pragma unroll
        for (int o = 0; o < 3; ++o)
            #pragma unroll
            for (int j = 0; j < 7; ++j) acc[o][j] = -1e30f;
        const float* xbase = s_in + c * PLANE + (2 * py + 3 * h) * ROWS + 14 * s;
        #pragma unroll
        for (int u = 0; u < 3; ++u) {
            float xv[18];
            #pragma unroll
            for (int i2 = 0; i2 < 9; ++i2)
                ((float2*)xv)[i2] = ((const float2*)(xbase + u * ROWS))[i2];
            #pragma unroll
            for (int o = 0; o < 3; ++o) {
                const float* wbase =
                    s_w1d + ((ocg * 3 + o) * 3 + c) * 36 + h * 18 + u * 6;
                float wv[6];
                #pragma unroll
                for (int i2 = 0; i2 < 3; ++i2)
                    ((float2*)wv)[i2] = ((const float2*)wbase)[i2];
                #pragma unroll
                for (int j = 0; j < 7; ++j) {
                    #pragma unroll
                    for (int ux = 0; ux < 6; ++ux)
                        acc[o][j] = fmaxf(acc[o][j], xv[2 * j + ux] + wv[ux]);
                }
            }
        }
        #pragma unroll
        for (int o = 0; o < 3; ++o) {
            const int obase = (ocg * 3 + o) * 196 + py * 14 + 7 * s;
            #pragma unroll
            for (int j = 0; j < 7; ++j) {
                const float rl = fmaxf(acc[o][j] - 1.0f, 0.0f);
                atomicMax(&s_a1u[obase + j], __float_as_uint(rl));
            }
        }
    }
    // prefetch w3 into registers (in flight through conv2 + barriers, used E)
    if (tid < 960) {
        const int o = tid >> 3, q = tid & 7;
        const float4* wv = (const float4*)(w3 + o * 400);
        #pragma unroll
        for (int i = 0; i < 13; ++i) {
            int l = q + 8 * i; if (l > 99) l = 99;
            w3p[i] = wv[l];
        }
    }
    // w2 dilation: 576 row-tasks on waves 7-15 (off conv1's waves 0-5)
    if (tid >= 448) {
        const int e = tid - 448;
        const int occ = e / 6, r = e - occ * 6;     // occ = oc*6+c
        dilate_row(s_w2r + occ * 25, r, s_w2d + occ * 36 + r * 6);
    }
    __syncthreads();

    // ---- Phase D: conv2 partials; 240 tasks (ocq,py,c,h), 4 oc per task,
    //      3 uy x 5-px row, x row loaded once per uy and reused across oc
    if (tid < 240) {
        const int ocq = tid / 60;
        const int r = tid - ocq * 60;
        const int py = r / 12;
        const int r2 = r - py * 12;
        const int c = r2 >> 1;
        const int h = r2 & 1;
        float acc[4][5];
        #pragma unroll
        for (int o = 0; o < 4; ++o)
            #pragma unroll
            for (int j = 0; j < 5; ++j) acc[o][j] = -1e30f;
        const float* a1f = (const float*)s_a1u;
        const float* xbase = a1f + c * 196 + (2 * py + 3 * h) * 14;
        #pragma unroll
        for (int u = 0; u < 3; ++u) {
            float xv[14];
            #pragma unroll
            for (int i2 = 0; i2 < 7; ++i2)
                ((float2*)xv)[i2] = ((const float2*)(xbase + u * 14))[i2];
            #pragma unroll
            for (int o = 0; o < 4; ++o) {
                const float* wbase =
                    s_w2d + ((ocq * 4 + o) * 6 + c) * 36 + h * 18 + u * 6;
                float wv[6];
                #pragma unroll
                for (int i2 = 0; i2 < 3; ++i2)
                    ((float2*)wv)[i2] = ((const float2*)wbase)[i2];
                #pragma unroll
                for (int j = 0; j < 5; ++j) {
                    #pragma unroll
                    for (int ux = 0; ux < 6; ++ux)
                        acc[o][j] = fmaxf(acc[o][j], xv[2 * j + ux] + wv[ux]);
                }
            }
        }
        #pragma unroll
        for (int o = 0; o < 4; ++o) {
            const int obase = (ocq * 4 + o) * 25 + py * 5;
            #pragma unroll
            for (int j = 0; j < 5; ++j) {
                const float rl = fmaxf(acc[o][j] - 1.0f, 0.0f);
                atomicMax(&s_a2u[obase + j], __float_as_uint(rl));
            }
        }
    }
    // prefetch wd for the dense phase (in flight during E)
    float wdp[15];
    if (tid < 672) {
        const int o = tid >> 3, q = tid & 7;
        #pragma unroll
        for (int i = 0; i < 15; ++i)
            wdp[i] = wd[(q * 15 + i) * 84 + o];
    }
    __syncthreads();

    // ---- Phase E: L3 [16,5,5]->[120]; 8 threads/output, prefetched w3
    if (tid < 960) {
        const int o = tid >> 3, q = tid & 7;
        const float4* av = (const float4*)(const float*)s_a2u;
        float m = -1e30f;
        #pragma unroll
        for (int i = 0; i < 13; ++i) {
            int l = q + 8 * i; if (l > 99) l = 99;
            const float4 a = av[l];
            const float4 w = w3p[i];
            m = fmaxf(m, fmaxf(fmaxf(a.x + w.x, a.y + w.y),
                               fmaxf(a.z + w.z, a.w + w.w)));
        }
        m = fmaxf(m, __shfl_xor(m, 1));
        m = fmaxf(m, __shfl_xor(m, 2));
        m = fmaxf(m, __shfl_xor(m, 4));
        if (q == 0) s_a3[o] = fmaxf(m - 1.0f, 0.0f);
    }
    __syncthreads();

    // ---- Phase F: dense [120]->[84] + tanh; 8 threads/output, prefetched wd
    if (tid < 672) {
        const int o = tid >> 3, q = tid & 7;
        float acc = 0.0f;
        #pragma unroll
        for (int i = 0; i < 15; ++i)
            acc = fmaf(s_a3[q * 15 + i], wdp[i], acc);
        acc += __shfl_xor(acc, 1);
        acc += __shfl_xor(acc, 2);
        acc += __shfl_xor(acc, 4);
        if (q == 0)
            s_a4[o] = 1.0f - 2.0f / (__expf(2.0f * acc) + 1.0f);  // tanh
    }
    __syncthreads();

    // ---- Phase G: fc [84]->[10] + bias + log_softmax, single wave, LDS-only
    if (tid < 64) {
        float acc = 0.0f;
        if (tid < 40) {
            const int o = tid >> 2, q = tid & 3;
            #pragma unroll 7
            for (int i = 0; i < 21; ++i) {
                const int k = q * 21 + i;
                acc = fmaf(s_a4[k], s_wf[k * 10 + o], acc);
            }
            acc += __shfl_xor(acc, 1);
            acc += __shfl_xor(acc, 2);
            acc += s_wf[840 + o];
        }
        const float lg = __shfl(acc, (tid < 10) ? tid * 4 : 0);
        if (tid < 16) {
            float v = (tid < 10) ? lg : -1e30f;
            #pragma unroll
            for (int d = 1; d < 16; d <<= 1)
                v = fmaxf(v, __shfl_xor(v, d));
            float e = (tid < 10) ? __expf(lg - v) : 0.0f;
            float ssum = e;
            #pragma unroll
            for (int d = 1; d < 16; d <<= 1)
                ssum += __shfl_xor(ssum, d);
            if (tid < 10)
                out[img * 10 + tid] = lg - v - __logf(ssum);
        }
    }
}

extern "C" void kernel_launch(void* const* d_in, const int* in_sizes, int n_in,
                              void* d_out, int out_size, void* d_ws, size_t ws_size,
                              hipStream_t stream) {
    const float* x   = (const float*)d_in[0];
    const float* w1  = (const float*)d_in[1];
    const float* w2  = (const float*)d_in[2];
    const float* w3  = (const float*)d_in[3];
    const float* wd  = (const float*)d_in[4];
    const float* wf  = (const float*)d_in[5];
    const float* bfv = (const float*)d_in[6];
    float* out = (float*)d_out;

    const int B = in_sizes[0] / (3 * 32 * 32);
    fused_lenet<<<dim3(B), dim3(NT), 0, stream>>>(
        x, w1, w2, w3, wd, wf, bfv, out);
}

// Round 13
// 74.182 us; speedup vs baseline: 1.2173x; 1.0000x over previous
//
#include <hip/hip_runtime.h>
#include <math.h>

// Fuzzy LeNet-5, Yager p=1 == Lukasiewicz: T(a,b)=max(0,a+b-1).
// Fuzzy conv == max-plus conv: out = relu(max_{c,kh,kw}(x+w) - 1).
// maxpool2 folds into the conv via dilated 6x6 weights:
//   W'[uy][ux] = max_{dy,dx in {0,1}, uy-dy,ux-dx in [0,5)} w[uy-dy][ux-dx]
//
// R12 post-mortem: C-window LDS pipe still carried w2 dilation (~117 wave-
// insts) + s_w2r staging. R13: dilate w2 straight from GLOBAL in phase A
// (same row-form as w1), delete s_w2r -- C-window is now pure conv1 + w3
// register prefetch. (h-shuffle atomic-combine was considered and rejected:
// __shfl lowers to ds_* ops -- same LDS pipe, net zero.)
// Channel/h-partials combined via LDS atomicMax on relu'd float bits (exact:
// relu>=0 floats order as uints; relu(max-1)=max(relu(p-1))).

#define NT 1024
#define ROWS 34                 // padded image row stride
#define PLANE (32 * ROWS)       // 1088

__device__ __forceinline__ void dilate_row(const float* __restrict__ raw,
                                           int r, float* __restrict__ dst) {
    // dst[0..5] = max over kh in {r-1,r} cap [0,4], kw in {col-1,col} cap [0,4]
    const int rA = (r > 0) ? r - 1 : 0;
    const int rB = (r < 5) ? r : 4;
    float t0 = fmaxf(raw[rA * 5 + 0], raw[rB * 5 + 0]);
    float t1 = fmaxf(raw[rA * 5 + 1], raw[rB * 5 + 1]);
    float t2 = fmaxf(raw[rA * 5 + 2], raw[rB * 5 + 2]);
    float t3 = fmaxf(raw[rA * 5 + 3], raw[rB * 5 + 3]);
    float t4 = fmaxf(raw[rA * 5 + 4], raw[rB * 5 + 4]);
    float2* d = (float2*)dst;
    d[0] = make_float2(t0, fmaxf(t0, t1));
    d[1] = make_float2(fmaxf(t1, t2), fmaxf(t2, t3));
    d[2] = make_float2(fmaxf(t3, t4), t4);
}

__global__ __launch_bounds__(NT) void fused_lenet(
    const float* __restrict__ x,   // [B,3,32,32]
    const float* __restrict__ w1,  // [6,3,5,5]
    const float* __restrict__ w2,  // [16,6,5,5]
    const float* __restrict__ w3,  // [120,16,5,5]
    const float* __restrict__ wd,  // [120,84]
    const float* __restrict__ wf,  // [84,10]
    const float* __restrict__ bfv, // [10]
    float* __restrict__ out)       // [B,10]
{
    const int img = blockIdx.x;
    const int tid = threadIdx.x;

    __shared__ float s_in[3 * PLANE];          // 13056 B
    __shared__ float s_w1d[648];               // [oc][c][uy][6]
    __shared__ float s_w2d[3456];              // [oc][c][uy][6]
    __shared__ float s_wf[850];                // wf[840] + bf[10]
    __shared__ unsigned s_a1u[1176];           // conv1 out, relu'd float bits
    __shared__ unsigned s_a2u[400];            // conv2 out, relu'd float bits
    __shared__ float s_a3[120];
    __shared__ float s_a4[84];

    float4 w3p[13];   // filled after conv1 body, consumed in phase E

    // ---- Phase A: stage image + wf/bf + zero accums + dilate w1 AND w2
    //      (both dilations read global directly; latency hides under staging)
    {
        const float2* src = (const float2*)(x + img * 3072);
        for (int i = tid; i < 1536; i += NT) {
            const int c = i >> 9, rem = i & 511, r = rem >> 4, col2 = rem & 15;
            ((float2*)s_in)[c * (PLANE / 2) + r * (ROWS / 2) + col2] = src[i];
        }
        if (tid < 420) ((float2*)s_wf)[tid] = ((const float2*)wf)[tid];
        if (tid >= 428 && tid < 438) s_wf[840 + tid - 428] = bfv[tid - 428];
        for (int i = tid; i < 1176; i += NT) s_a1u[i] = 0u;
        if (tid < 400) s_a2u[tid] = 0u;
        if (tid >= 320 && tid < 428) {          // w1 dilation: 108 row-tasks
            const int e = tid - 320;
            const int occ = e / 6, r = e - occ * 6;   // occ = oc*3+c
            dilate_row(w1 + occ * 25, r, s_w1d + occ * 36 + r * 6);
        }
        if (tid >= 448) {                       // w2 dilation: 576 row-tasks
            const int e = tid - 448;
            const int occ = e / 6, r = e - occ * 6;   // occ = oc*6+c
            dilate_row(w2 + occ * 25, r, s_w2d + occ * 36 + r * 6);
        }
    }
    __syncthreads();

    // ---- Phase C: conv1 partials; 336 tasks (c,ocg,py,s,h), 3 oc per task,
    //      3 uy x 7-px strip, x row loaded once per uy and reused across oc
    if (tid < 336) {
        const int c = tid / 112;
        const int r = tid - c * 112;
        const int ocg = r / 56;
        const int r2 = r - ocg * 56;
        const int py = r2 >> 2;
        const int s = (r2 >> 1) & 1;
        const int h = r2 & 1;
        float acc[3][7];
        #pragma unroll
        for (int o = 0; o < 3; ++o)
            #pragma unroll
            for (int j = 0; j < 7; ++j) acc[o][j] = -1e30f;
        const float* xbase = s_in + c * PLANE + (2 * py + 3 * h) * ROWS + 14 * s;
        #pragma unroll
        for (int u = 0; u < 3; ++u) {
            float xv[18];
            #pragma unroll
            for (int i2 = 0; i2 < 9; ++i2)
                ((float2*)xv)[i2] = ((const float2*)(xbase + u * ROWS))[i2];
            #pragma unroll
            for (int o = 0; o < 3; ++o) {
                const float* wbase =
                    s_w1d + ((ocg * 3 + o) * 3 + c) * 36 + h * 18 + u * 6;
                float wv[6];
                #pragma unroll
                for (int i2 = 0; i2 < 3; ++i2)
                    ((float2*)wv)[i2] = ((const float2*)wbase)[i2];
                #pragma unroll
                for (int j = 0; j < 7; ++j) {
                    #pragma unroll
                    for (int ux = 0; ux < 6; ++ux)
                        acc[o][j] = fmaxf(acc[o][j], xv[2 * j + ux] + wv[ux]);
                }
            }
        }
        #pragma unroll
        for (int o = 0; o < 3; ++o) {
            const int obase = (ocg * 3 + o) * 196 + py * 14 + 7 * s;
            #pragma unroll
            for (int j = 0; j < 7; ++j) {
                const float rl = fmaxf(acc[o][j] - 1.0f, 0.0f);
                atomicMax(&s_a1u[obase + j], __float_as_uint(rl));
            }
        }
    }
    // prefetch w3 into registers (in flight through conv2 + barriers, used E)
    if (tid < 960) {
        const int o = tid >> 3, q = tid & 7;
        const float4* wv = (const float4*)(w3 + o * 400);
        #pragma unroll
        for (int i = 0; i < 13; ++i) {
            int l = q + 8 * i; if (l > 99) l = 99;
            w3p[i] = wv[l];
        }
    }
    __syncthreads();

    // ---- Phase D: conv2 partials; 240 tasks (ocq,py,c,h), 4 oc per task,
    //      3 uy x 5-px row, x row loaded once per uy and reused across oc
    if (tid < 240) {
        const int ocq = tid / 60;
        const int r = tid - ocq * 60;
        const int py = r / 12;
        const int r2 = r - py * 12;
        const int c = r2 >> 1;
        const int h = r2 & 1;
        float acc[4][5];
        #pragma unroll
        for (int o = 0; o < 4; ++o)
            #pragma unroll
            for (int j = 0; j < 5; ++j) acc[o][j] = -1e30f;
        const float* a1f = (const float*)s_a1u;
        const float* xbase = a1f + c * 196 + (2 * py + 3 * h) * 14;
        #pragma unroll
        for (int u = 0; u < 3; ++u) {
            float xv[14];
            #pragma unroll
            for (int i2 = 0; i2 < 7; ++i2)
                ((float2*)xv)[i2] = ((const float2*)(xbase + u * 14))[i2];
            #pragma unroll
            for (int o = 0; o < 4; ++o) {
                const float* wbase =
                    s_w2d + ((ocq * 4 + o) * 6 + c) * 36 + h * 18 + u * 6;
                float wv[6];
                #pragma unroll
                for (int i2 = 0; i2 < 3; ++i2)
                    ((float2*)wv)[i2] = ((const float2*)wbase)[i2];
                #pragma unroll
                for (int j = 0; j < 5; ++j) {
                    #pragma unroll
                    for (int ux = 0; ux < 6; ++ux)
                        acc[o][j] = fmaxf(acc[o][j], xv[2 * j + ux] + wv[ux]);
                }
            }
        }
        #pragma unroll
        for (int o = 0; o < 4; ++o) {
            const int obase = (ocq * 4 + o) * 25 + py * 5;
            #pragma unroll
            for (int j = 0; j < 5; ++j) {
                const float rl = fmaxf(acc[o][j] - 1.0f, 0.0f);
                atomicMax(&s_a2u[obase + j], __float_as_uint(rl));
            }
        }
    }
    // prefetch wd for the dense phase (in flight during E)
    float wdp[15];
    if (tid < 672) {
        const int o = tid >> 3, q = tid & 7;
        #pragma unroll
        for (int i = 0; i < 15; ++i)
            wdp[i] = wd[(q * 15 + i) * 84 + o];
    }
    __syncthreads();

    // ---- Phase E: L3 [16,5,5]->[120]; 8 threads/output, prefetched w3
    if (tid < 960) {
        const int o = tid >> 3, q = tid & 7;
        const float4* av = (const float4*)(const float*)s_a2u;
        float m = -1e30f;
        #pragma unroll
        for (int i = 0; i < 13; ++i) {
            int l = q + 8 * i; if (l > 99) l = 99;
            const float4 a = av[l];
            const float4 w = w3p[i];
            m = fmaxf(m, fmaxf(fmaxf(a.x + w.x, a.y + w.y),
                               fmaxf(a.z + w.z, a.w + w.w)));
        }
        m = fmaxf(m, __shfl_xor(m, 1));
        m = fmaxf(m, __shfl_xor(m, 2));
        m = fmaxf(m, __shfl_xor(m, 4));
        if (q == 0) s_a3[o] = fmaxf(m - 1.0f, 0.0f);
    }
    __syncthreads();

    // ---- Phase F: dense [120]->[84] + tanh; 8 threads/output, prefetched wd
    if (tid < 672) {
        const int o = tid >> 3, q = tid & 7;
        float acc = 0.0f;
        #pragma unroll
        for (int i = 0; i < 15; ++i)
            acc = fmaf(s_a3[q * 15 + i], wdp[i], acc);
        acc += __shfl_xor(acc, 1);
        acc += __shfl_xor(acc, 2);
        acc += __shfl_xor(acc, 4);
        if (q == 0)
            s_a4[o] = 1.0f - 2.0f / (__expf(2.0f * acc) + 1.0f);  // tanh
    }
    __syncthreads();

    // ---- Phase G: fc [84]->[10] + bias + log_softmax, single wave, LDS-only
    if (tid < 64) {
        float acc = 0.0f;
        if (tid < 40) {
            const int o = tid >> 2, q = tid & 3;
            #pragma unroll 7
            for (int i = 0; i < 21; ++i) {
                const int k = q * 21 + i;
                acc = fmaf(s_a4[k], s_wf[k * 10 + o], acc);
            }
            acc += __shfl_xor(acc, 1);
            acc += __shfl_xor(acc, 2);
            acc += s_wf[840 + o];
        }
        const float lg = __shfl(acc, (tid < 10) ? tid * 4 : 0);
        if (tid < 16) {
            float v = (tid < 10) ? lg : -1e30f;
            #pragma unroll
            for (int d = 1; d < 16; d <<= 1)
                v = fmaxf(v, __shfl_xor(v, d));
            float e = (tid < 10) ? __expf(lg - v) : 0.0f;
            float ssum = e;
            #pragma unroll
            for (int d = 1; d < 16; d <<= 1)
                ssum += __shfl_xor(ssum, d);
            if (tid < 10)
                out[img * 10 + tid] = lg - v - __logf(ssum);
        }
    }
}

extern "C" void kernel_launch(void* const* d_in, const int* in_sizes, int n_in,
                              void* d_out, int out_size, void* d_ws, size_t ws_size,
                              hipStream_t stream) {
    const float* x   = (const float*)d_in[0];
    const float* w1  = (const float*)d_in[1];
    const float* w2  = (const float*)d_in[2];
    const float* w3  = (const float*)d_in[3];
    const float* wd  = (const float*)d_in[4];
    const float* wf  = (const float*)d_in[5];
    const float* bfv = (const float*)d_in[6];
    float* out = (float*)d_out;

    const int B = in_sizes[0] / (3 * 32 * 32);
    fused_lenet<<<dim3(B), dim3(NT), 0, stream>>>(
        x, w1, w2, w3, wd, wf, bfv, out);
}